// Round 1
// baseline (1828.384 us; speedup 1.0000x reference)
//
#include <hip/hip_runtime.h>

// LSTM decoder: B=256, H=512, L=2, T=64, O=7
// Strategy: fp16 MFMA (16x16x32) GEMM fused with LSTM cell, fp32 accumulate.
// Multi-launch baseline: 2 layer kernels per timestep + prologue + final FC.

#define BB 256
#define HH 512
#define NG 2048   // 4*H
#define KK 1024   // 2*H (concat [x, h])
#define TT 64
#define NO 7

typedef _Float16 h16;
typedef __attribute__((ext_vector_type(8))) _Float16 half8;
typedef __attribute__((ext_vector_type(4))) float f32x4;

// ---------------- prologue: pack [W_ih | W_hh] -> f16 Wc[l][n][k], k-major ----
__global__ __launch_bounds__(256) void prep_weights(
    const float* __restrict__ Wih, const float* __restrict__ Whh,
    h16* __restrict__ Wc)
{
    // one thread per 8 halfs; total 2*2048*1024/8 = 524288 threads
    size_t gid = (size_t)blockIdx.x * 256 + threadIdx.x;
    size_t base = gid * 8;
    int l = (int)(base >> 21);            // 2048*1024 = 2^21 per layer
    int rem = (int)(base & ((1u << 21) - 1));
    int n = rem >> 10;
    int k = rem & 1023;
    const float* src = (k < 512)
        ? (Wih + ((size_t)l * NG + n) * 512 + k)
        : (Whh + ((size_t)l * NG + n) * 512 + (k - 512));
    const float4* s4 = (const float4*)src;
    float4 a = s4[0];
    float4 b = s4[1];
    half8 o;
    o[0] = (h16)a.x; o[1] = (h16)a.y; o[2] = (h16)a.z; o[3] = (h16)a.w;
    o[4] = (h16)b.x; o[5] = (h16)b.y; o[6] = (h16)b.z; o[7] = (h16)b.w;
    *(half8*)(Wc + base) = o;
}

// ---------------- prologue: init A-buffers, h/c state, bias ------------------
__global__ __launch_bounds__(256) void init_misc(
    const float* __restrict__ x, const float* __restrict__ h0,
    const float* __restrict__ c0, const float* __restrict__ bih,
    const float* __restrict__ bhh,
    h16* __restrict__ A0, h16* __restrict__ A1,
    float* __restrict__ h_st, float* __restrict__ c_st,
    float* __restrict__ bias)
{
    int i = blockIdx.x * 256 + threadIdx.x;
    if (i < 262144) {              // A0[0][b][k] = [x | h0_layer0]
        int b = i >> 10, k = i & 1023;
        float v = (k < 512) ? x[b * 512 + k] : h0[b * 512 + (k - 512)];
        A0[i] = (h16)v;
        return;
    }
    i -= 262144;
    if (i < 131072) {              // A1[0][b][512+u] = h0_layer1
        int b = i >> 9, u = i & 511;
        A1[b * 1024 + 512 + u] = (h16)h0[131072 + i];
        return;
    }
    i -= 131072;
    if (i < 262144) { h_st[i] = h0[i]; return; }
    i -= 262144;
    if (i < 262144) { c_st[i] = c0[i]; return; }
    i -= 262144;
    if (i < 4096) bias[i] = bih[i] + bhh[i];
}

// ---------------- fused GEMM + LSTM cell for one layer-step ------------------
// grid: (32, 4): blockIdx.x = h-slice of 16 units, blockIdx.y = 64-row M tile.
// WG tile: 64 batch rows x {4 gate groups x 16 h-units} -> cell is lane-local.
__global__ __launch_bounds__(256) void lstm_layer(
    const h16* __restrict__ A, const h16* __restrict__ W,
    const float* __restrict__ bias,
    float* __restrict__ c_st, float* __restrict__ h_st,
    h16* __restrict__ dst1, int off1,
    h16* __restrict__ dst2, int off2,
    float* __restrict__ h1all)
{
    __shared__ h16 As[64][72];   // 64 rows x 64 k, stride 72 halfs (144 B)
    __shared__ h16 Bs[64][72];   // 64 gate-cols (4 groups x 16 units) x 64 k

    const int tid  = threadIdx.x;
    const int wave = tid >> 6;
    const int lane = tid & 63;
    const int hs   = blockIdx.x * 16;   // h-unit slice start
    const int m0   = blockIdx.y * 64;   // batch tile start

    f32x4 acc[4] = {f32x4{0,0,0,0}, f32x4{0,0,0,0}, f32x4{0,0,0,0}, f32x4{0,0,0,0}};

    // staging indices: 512 chunks of 16B, 2 per thread
    const int e0 = tid,        r0 = e0 >> 3, kq0 = (e0 & 7) * 8;
    const int e1 = tid + 256,  r1 = e1 >> 3, kq1 = (e1 & 7) * 8;
    const int n0 = ((r0 >> 4) * 512) + hs + (r0 & 15);   // weight row for Bs[r0]
    const int n1 = ((r1 >> 4) * 512) + hs + (r1 & 15);
    const int mrow = wave * 16 + (lane & 15);
    const int koff = (lane >> 4) * 8;

    for (int kt = 0; kt < 16; ++kt) {
        const int k0 = kt * 64;
        if (kt) __syncthreads();
        *(half8*)&As[r0][kq0] = *(const half8*)(A + (size_t)(m0 + r0) * 1024 + k0 + kq0);
        *(half8*)&As[r1][kq1] = *(const half8*)(A + (size_t)(m0 + r1) * 1024 + k0 + kq1);
        *(half8*)&Bs[r0][kq0] = *(const half8*)(W + (size_t)n0 * 1024 + k0 + kq0);
        *(half8*)&Bs[r1][kq1] = *(const half8*)(W + (size_t)n1 * 1024 + k0 + kq1);
        __syncthreads();
#pragma unroll
        for (int ks = 0; ks < 2; ++ks) {
            half8 a = *(const half8*)&As[mrow][ks * 32 + koff];
#pragma unroll
            for (int g = 0; g < 4; ++g) {
                half8 b = *(const half8*)&Bs[g * 16 + (lane & 15)][ks * 32 + koff];
                acc[g] = __builtin_amdgcn_mfma_f32_16x16x32_f16(a, b, acc[g], 0, 0, 0);
            }
        }
    }

    // epilogue: lane holds gates i/f/g/o for h-unit u, rows q*4+r of its wave tile
    const int u  = hs + (lane & 15);
    const int q  = lane >> 4;
    const float bi = bias[u];
    const float bf = bias[512 + u];
    const float bg = bias[1024 + u];
    const float bo = bias[1536 + u];
#pragma unroll
    for (int r = 0; r < 4; ++r) {
        const int brow = m0 + wave * 16 + q * 4 + r;
        float gi = acc[0][r] + bi;
        float gf = acc[1][r] + bf;
        float gg = acc[2][r] + bg;
        float go = acc[3][r] + bo;
        float iv = 1.f / (1.f + __expf(-gi));
        float fv = 1.f / (1.f + __expf(-gf));
        float gv = 1.f - 2.f / (__expf(2.f * gg) + 1.f);   // tanh, overflow-safe
        float ov = 1.f / (1.f + __expf(-go));
        float c  = fv * c_st[brow * 512 + u] + iv * gv;
        float h  = ov * (1.f - 2.f / (__expf(2.f * c) + 1.f));
        c_st[brow * 512 + u] = c;
        h_st[brow * 512 + u] = h;
        h16 hh = (h16)h;
        dst1[(size_t)brow * 1024 + off1 + u] = hh;
        dst2[(size_t)brow * 1024 + off2 + u] = hh;
        if (h1all) h1all[brow * 512 + u] = h;
    }
}

// ---------------- final FC over all stored h1(t): (T*B) x 7, K=512 -----------
__global__ __launch_bounds__(256) void fc_kernel(
    const float* __restrict__ h1all, const float* __restrict__ Wfc,
    const float* __restrict__ bfc, float* __restrict__ out)
{
    __shared__ float wl[NO * 512];
    for (int i = threadIdx.x; i < NO * 512; i += 256) wl[i] = Wfc[i];
    __syncthreads();
    const int wave = threadIdx.x >> 6, lane = threadIdx.x & 63;
    const int row = blockIdx.x * 4 + wave;   // row = t*256 + b
    const float* hr = h1all + (size_t)row * 512;
    float acc[NO] = {0, 0, 0, 0, 0, 0, 0};
#pragma unroll
    for (int i = 0; i < 8; ++i) {
        float hv = hr[i * 64 + lane];
#pragma unroll
        for (int o = 0; o < NO; ++o) acc[o] += hv * wl[o * 512 + i * 64 + lane];
    }
#pragma unroll
    for (int o = 0; o < NO; ++o)
#pragma unroll
        for (int off = 32; off; off >>= 1) acc[o] += __shfl_down(acc[o], off);
    if (lane == 0) {
        const int t = row >> 8, b = row & 255;
#pragma unroll
        for (int o = 0; o < NO; ++o) out[b * (TT * NO) + t * NO + o] = acc[o] + bfc[o];
    }
}

extern "C" void kernel_launch(void* const* d_in, const int* in_sizes, int n_in,
                              void* d_out, int out_size, void* d_ws, size_t ws_size,
                              hipStream_t stream)
{
    (void)in_sizes; (void)n_in; (void)out_size; (void)ws_size;
    const float* x   = (const float*)d_in[0];
    const float* h0  = (const float*)d_in[1];
    const float* c0  = (const float*)d_in[2];
    const float* Wih = (const float*)d_in[3];
    const float* Whh = (const float*)d_in[4];
    const float* bih = (const float*)d_in[5];
    const float* bhh = (const float*)d_in[6];
    const float* Wfc = (const float*)d_in[7];
    const float* bfc = (const float*)d_in[8];
    // seq_len (d_in[9]) is fixed at 64 by setup_inputs; hardcoded.

    float* outf = (float*)d_out;                 // decoded (256*64*7)
    float* h_st = outf + 114688;                 // hT (2,256,512)
    float* c_st = h_st + 262144;                 // cT (2,256,512)

    char* ws = (char*)d_ws;
    h16*   Wc    = (h16*)ws;                                   // 8 MB
    float* bias  = (float*)(ws + 8388608);                     // 16 KB
    h16*   A0    = (h16*)(ws + 8388608 + 16384);               // 2 x 512 KB
    h16*   A1    = (h16*)(ws + 8388608 + 16384 + 1048576);     // 2 x 512 KB
    float* h1all = (float*)(ws + 8388608 + 16384 + 2097152);   // 32 MB

    prep_weights<<<2048, 256, 0, stream>>>(Wih, Whh, Wc);
    init_misc<<<3600, 256, 0, stream>>>(x, h0, c0, bih, bhh, A0, A1, h_st, c_st, bias);

    const int AS = 262144;    // halfs per A parity buffer
    const int WS = 2097152;   // halfs per layer weight block
    const int CS = 131072;    // floats per layer state block
    for (int t = 0; t < TT; ++t) {
        int p = t & 1, q = p ^ 1;
        // layer 0: reads A0[p]; h0' -> A1[p] x-part, A0[q] h-part
        lstm_layer<<<dim3(32, 4), 256, 0, stream>>>(
            A0 + (size_t)p * AS, Wc, bias, c_st, h_st,
            A1 + (size_t)p * AS, 0, A0 + (size_t)q * AS, 512, (float*)nullptr);
        // layer 1: reads A1[p]; h1' -> A0[q] x-part, A1[q] h-part, h1all[t]
        lstm_layer<<<dim3(32, 4), 256, 0, stream>>>(
            A1 + (size_t)p * AS, Wc + WS, bias + 2048, c_st + CS, h_st + CS,
            A0 + (size_t)q * AS, 0, A1 + (size_t)q * AS, 512, h1all + (size_t)t * CS);
    }
    fc_kernel<<<4096, 256, 0, stream>>>(h1all, Wfc, bfc, outf);
}